// Round 2
// baseline (2702.981 us; speedup 1.0000x reference)
//
#include <hip/hip_runtime.h>

// Problem constants (reference: HIDDEN=2048, N_HEADS=16, HEAD_DIM=128,
// ROTARY_DIM=32, base=1e4, NEG_INF=-1e4, B=2, S=2048).
// DTYPES (round-2 correction): inputs fp32, output fp32 (per reference).
// Internals: q/k/v staged as bf16 (MFMA-friendly), all accumulation fp32.
#define B_    2
#define S_    2048
#define E_    2048
#define NH_   16
#define HD_   128
#define NQKV_ 6144           // 3*E
#define M_    4096           // B*S

typedef short bf16x8 __attribute__((ext_vector_type(8)));   // 8 bf16 (4 VGPRs)
typedef float f32x4  __attribute__((ext_vector_type(4)));   // MFMA C/D

__device__ inline float b2f(unsigned short u) {
    return __uint_as_float(((unsigned int)u) << 16);
}
__device__ inline unsigned short f2b(float f) {             // RNE f32->bf16
    unsigned int x = __float_as_uint(f);
    x = x + 0x7fffu + ((x >> 16) & 1u);
    return (unsigned short)(x >> 16);
}
__device__ inline unsigned int pk2(float lo, float hi) {    // pack 2 bf16
    return (unsigned int)f2b(lo) | ((unsigned int)f2b(hi) << 16);
}

// ---------------------------------------------------------------------------
// Kernel 1: QKV = X(4096x2048 fp32) * W^T(2048x6144 fp32) + bias, bf16 MFMA.
// fp32 loads are converted to bf16 in-register during LDS staging.
// 128x128 tile, BK=32, 4 waves (2x2 of 64x64), mfma_f32_16x16x32_bf16.
// Verified layouts: A-frag A[m=lane&15][k=(lane>>4)*8+j]; W rows give B^T
// fragments with the same pattern; C/D row=(lane>>4)*4+reg, col=lane&15.
// Epilogue adds fp32 bias, scatters bf16 into q/k/v buffers [B][NH][S][HD].
// ---------------------------------------------------------------------------
__global__ __launch_bounds__(256, 2) void qkv_gemm(
    const float* __restrict__ X,
    const float* __restrict__ W,
    const float* __restrict__ bias,
    unsigned short* __restrict__ qb,
    unsigned short* __restrict__ kb,
    unsigned short* __restrict__ vb)
{
    __shared__ __align__(16) unsigned short As[128 * 32];
    __shared__ __align__(16) unsigned short Bs[128 * 32];

    const int t    = threadIdx.x;
    const int lane = t & 63;
    const int wave = t >> 6;
    const int m0   = blockIdx.y * 128;
    const int n0   = blockIdx.x * 128;
    const int wm   = (wave >> 1) * 64;
    const int wn   = (wave & 1) * 64;
    const int quad = lane >> 4;
    const int l16  = lane & 15;

    // staging: thread covers rows {srow, srow+64}, cols [scol, scol+8)
    const int srow = t >> 2;          // 0..63
    const int scol = (t & 3) * 8;     // 0,8,16,24

    const float* Ap = X + (m0 + srow) * E_ + scol;
    const float* Bp = W + (n0 + srow) * E_ + scol;

    f32x4 acc[4][4];
    #pragma unroll
    for (int i = 0; i < 4; i++)
        #pragma unroll
        for (int j = 0; j < 4; j++)
            #pragma unroll
            for (int r = 0; r < 4; r++) acc[i][j][r] = 0.0f;

    for (int k0 = 0; k0 < E_; k0 += 32) {
        float4 a00 = *(const float4*)(Ap + k0);
        float4 a01 = *(const float4*)(Ap + k0 + 4);
        float4 a10 = *(const float4*)(Ap + k0 + 64 * E_);
        float4 a11 = *(const float4*)(Ap + k0 + 64 * E_ + 4);
        float4 b00 = *(const float4*)(Bp + k0);
        float4 b01 = *(const float4*)(Bp + k0 + 4);
        float4 b10 = *(const float4*)(Bp + k0 + 64 * E_);
        float4 b11 = *(const float4*)(Bp + k0 + 64 * E_ + 4);
        __syncthreads();
        {
            uint4 pa0 = { pk2(a00.x, a00.y), pk2(a00.z, a00.w),
                          pk2(a01.x, a01.y), pk2(a01.z, a01.w) };
            uint4 pa1 = { pk2(a10.x, a10.y), pk2(a10.z, a10.w),
                          pk2(a11.x, a11.y), pk2(a11.z, a11.w) };
            uint4 pb0 = { pk2(b00.x, b00.y), pk2(b00.z, b00.w),
                          pk2(b01.x, b01.y), pk2(b01.z, b01.w) };
            uint4 pb1 = { pk2(b10.x, b10.y), pk2(b10.z, b10.w),
                          pk2(b11.x, b11.y), pk2(b11.z, b11.w) };
            *(uint4*)&As[srow * 32 + scol]        = pa0;
            *(uint4*)&As[(srow + 64) * 32 + scol] = pa1;
            *(uint4*)&Bs[srow * 32 + scol]        = pb0;
            *(uint4*)&Bs[(srow + 64) * 32 + scol] = pb1;
        }
        __syncthreads();

        bf16x8 af[4], bfr[4];
        #pragma unroll
        for (int i = 0; i < 4; i++)
            af[i]  = *(const bf16x8*)&As[(wm + i * 16 + l16) * 32 + quad * 8];
        #pragma unroll
        for (int i = 0; i < 4; i++)
            bfr[i] = *(const bf16x8*)&Bs[(wn + i * 16 + l16) * 32 + quad * 8];

        #pragma unroll
        for (int i = 0; i < 4; i++)
            #pragma unroll
            for (int j = 0; j < 4; j++)
                acc[i][j] = __builtin_amdgcn_mfma_f32_16x16x32_bf16(
                    af[i], bfr[j], acc[i][j], 0, 0, 0);
    }

    // epilogue: fp32 bias + scatter to q/k/v [B][NH][S][HD] bf16
    #pragma unroll
    for (int j = 0; j < 4; j++) {
        const int n = n0 + wn + j * 16 + l16;           // 0..6143
        const float bv = bias[n];
        const int which = n >> 11;                      // 0=q 1=k 2=v
        const int h = (n >> 7) & 15;
        const int d = n & 127;
        unsigned short* dst = (which == 0) ? qb : ((which == 1) ? kb : vb);
        #pragma unroll
        for (int i = 0; i < 4; i++) {
            #pragma unroll
            for (int r = 0; r < 4; r++) {
                const int m  = m0 + wm + i * 16 + quad * 4 + r;  // 0..4095
                const int bb = m >> 11;
                const int s  = m & (S_ - 1);
                dst[((bb * NH_ + h) * S_ + s) * HD_ + d] = f2b(acc[i][j][r] + bv);
            }
        }
    }
}

// ---------------------------------------------------------------------------
// Kernel 2: in-place RoPE on q and k (bf16 buffers, fp32 math).
// thread = (bh, s, i), i in [0,16):
// out[i] = u[i]*cos - u[i+16]*sin ; out[i+16] = u[i]*sin + u[i+16]*cos
// angle = s * 10000^(-i/16)
// ---------------------------------------------------------------------------
__global__ void rope_inplace(unsigned short* __restrict__ qb,
                             unsigned short* __restrict__ kb)
{
    const int idx = blockIdx.x * 256 + threadIdx.x;     // B*NH*S*16 exactly
    const int i   = idx & 15;
    const int s   = (idx >> 4) & (S_ - 1);
    const int bh  = idx >> 15;
    const float inv = exp2f(-0.83048202372184059f * (float)i); // log2(1e4)/16
    const float ang = (float)s * inv;
    const float c  = cosf(ang);
    const float sn = sinf(ang);
    const int base = (bh * S_ + s) * HD_;
    {
        float u1 = b2f(qb[base + i]), u2 = b2f(qb[base + i + 16]);
        qb[base + i]      = f2b(u1 * c - u2 * sn);
        qb[base + i + 16] = f2b(u1 * sn + u2 * c);
    }
    {
        float u1 = b2f(kb[base + i]), u2 = b2f(kb[base + i + 16]);
        kb[base + i]      = f2b(u1 * c - u2 * sn);
        kb[base + i + 16] = f2b(u1 * sn + u2 * c);
    }
}

// ---------------------------------------------------------------------------
// Kernel 3: causal flash attention, vector fp32 (correctness-first; MFMA
// upgrade planned once green). Block = 256 = 64 q-rows x 4 col-slices of 32.
// Online softmax per row; 4 threads of a row shuffle-reduce dot products.
// -1e4 additive mask on the diagonal tile matches reference NEG_INF.
// Output written as fp32 float4.
// ---------------------------------------------------------------------------
__global__ __launch_bounds__(256, 2) void attn_flash(
    const unsigned short* __restrict__ qb,
    const unsigned short* __restrict__ kb,
    const unsigned short* __restrict__ vb,
    float* __restrict__ out)
{
    __shared__ __align__(16) unsigned short Ks[64 * 128];
    __shared__ __align__(16) unsigned short Vs[64 * 128];

    const int qt   = blockIdx.x;        // 0..31
    const int bh   = blockIdx.y;        // 0..31 = b*16+h
    const int b    = bh >> 4;
    const int h    = bh & 15;
    const int t    = threadIdx.x;
    const int lane = t & 63;
    const int ro   = t >> 2;            // 0..63
    const int co   = (t & 3) * 32;      // 0,32,64,96
    const int qabs = qt * 64 + ro;

    // Q slice -> registers, pre-scaled by 1/sqrt(128)
    float qreg[32];
    {
        const unsigned int* qp = (const unsigned int*)(qb + (bh * S_ + qabs) * HD_ + co);
        #pragma unroll
        for (int jj = 0; jj < 16; jj++) {
            unsigned int w = qp[jj];
            qreg[2 * jj]     = __uint_as_float(w << 16)          * 0.088388347648318447f;
            qreg[2 * jj + 1] = __uint_as_float(w & 0xffff0000u)  * 0.088388347648318447f;
        }
    }

    float o[32];
    #pragma unroll
    for (int j = 0; j < 32; j++) o[j] = 0.0f;
    float mrun = -1e30f, lrun = 0.0f;

    for (int kt = 0; kt <= qt; kt++) {
        __syncthreads();
        {   // stage 64x128 K and V tiles (64B per thread each)
            const uint4* kg = (const uint4*)(kb + (bh * S_ + kt * 64 + ro) * HD_ + co);
            const uint4* vg = (const uint4*)(vb + (bh * S_ + kt * 64 + ro) * HD_ + co);
            uint4* ks = (uint4*)&Ks[ro * 128 + co];
            uint4* vs = (uint4*)&Vs[ro * 128 + co];
            #pragma unroll
            for (int u = 0; u < 4; u++) { ks[u] = kg[u]; vs[u] = vg[u]; }
        }
        __syncthreads();

        float p_own[16];
        float mtile = -1e30f;
        const bool diag = (kt == qt);
        for (int kk = 0; kk < 64; kk++) {
            const unsigned int* kr = (const unsigned int*)&Ks[kk * 128 + co];
            float acc = 0.0f;
            #pragma unroll
            for (int jj = 0; jj < 16; jj++) {
                unsigned int w = kr[jj];
                acc += qreg[2 * jj]     * __uint_as_float(w << 16);
                acc += qreg[2 * jj + 1] * __uint_as_float(w & 0xffff0000u);
            }
            acc += __shfl_xor(acc, 1);
            acc += __shfl_xor(acc, 2);
            if (diag && (qt * 64 + kk > qabs)) acc += -10000.0f;
            if ((kk & 3) == (t & 3)) p_own[kk >> 2] = acc;
            mtile = fmaxf(mtile, acc);
        }

        const float mnew  = fmaxf(mrun, mtile);
        const float alpha = __expf(mrun - mnew);
        float lsum = 0.0f;
        #pragma unroll
        for (int i = 0; i < 16; i++) {
            p_own[i] = __expf(p_own[i] - mnew);
            lsum += p_own[i];
        }
        lsum += __shfl_xor(lsum, 1);
        lsum += __shfl_xor(lsum, 2);
        lrun = lrun * alpha + lsum;
        mrun = mnew;
        #pragma unroll
        for (int j = 0; j < 32; j++) o[j] *= alpha;

        #pragma unroll 4
        for (int i = 0; i < 16; i++) {
            #pragma unroll
            for (int q = 0; q < 4; q++) {
                const float p = __shfl(p_own[i], (lane & ~3) + q);
                const unsigned int* vr = (const unsigned int*)&Vs[(i * 4 + q) * 128 + co];
                #pragma unroll
                for (int jj = 0; jj < 16; jj++) {
                    unsigned int w = vr[jj];
                    o[2 * jj]     += p * __uint_as_float(w << 16);
                    o[2 * jj + 1] += p * __uint_as_float(w & 0xffff0000u);
                }
            }
        }
    }

    const float invl = 1.0f / lrun;
    float* op = out + (b * S_ + qabs) * E_ + h * HD_ + co;
    #pragma unroll
    for (int jj = 0; jj < 8; jj++) {
        float4 v4;
        v4.x = o[4 * jj]     * invl;
        v4.y = o[4 * jj + 1] * invl;
        v4.z = o[4 * jj + 2] * invl;
        v4.w = o[4 * jj + 3] * invl;
        *(float4*)(op + 4 * jj) = v4;
    }
}

// ---------------------------------------------------------------------------
extern "C" void kernel_launch(void* const* d_in, const int* in_sizes, int n_in,
                              void* d_out, int out_size, void* d_ws, size_t ws_size,
                              hipStream_t stream)
{
    const float* x    = (const float*)d_in[0];   // fp32 (B,S,E)
    const float* W    = (const float*)d_in[1];   // fp32 (6144,2048)
    const float* bias = (const float*)d_in[2];   // fp32 (6144,)
    float* out = (float*)d_out;                  // fp32 (B,S,E)

    const size_t per = (size_t)B_ * NH_ * S_ * HD_;               // 8388608 elems
    unsigned short* qb = (unsigned short*)d_ws;                   // [B][NH][S][HD]
    unsigned short* kb = qb + per;
    unsigned short* vb = kb + per;                                // 48 MB of ws

    dim3 gemm_grid(NQKV_ / 128, M_ / 128);                        // 48 x 32
    qkv_gemm<<<gemm_grid, 256, 0, stream>>>(x, W, bias, qb, kb, vb);

    rope_inplace<<<(B_ * NH_ * S_ * 16) / 256, 256, 0, stream>>>(qb, kb);

    dim3 attn_grid(S_ / 64, B_ * NH_);                            // 32 x 32
    attn_flash<<<attn_grid, 256, 0, stream>>>(qb, kb, vb, out);
}

// Round 3
// 608.225 us; speedup vs baseline: 4.4440x; 4.4440x over previous
//
#include <hip/hip_runtime.h>

// MHA: QKV GEMM (fp32 in, bf16 MFMA) -> RoPE -> MFMA flash attention (fp32 out)
// B=2 S=2048 E=2048 NH=16 HD=128 ROTARY=32 base=1e4 NEG_INF=-1e4
#define B_    2
#define S_    2048
#define E_    2048
#define NH_   16
#define HD_   128
#define NQKV_ 6144
#define M_    4096

typedef short bf16x8 __attribute__((ext_vector_type(8)));   // 8 bf16 (4 VGPRs)
typedef float f32x4  __attribute__((ext_vector_type(4)));   // MFMA C/D

__device__ inline float b2f(unsigned short u) {
    return __uint_as_float(((unsigned int)u) << 16);
}
__device__ inline unsigned short f2b(float f) {             // RNE f32->bf16
    unsigned int x = __float_as_uint(f);
    x = x + 0x7fffu + ((x >> 16) & 1u);
    return (unsigned short)(x >> 16);
}
__device__ inline unsigned int pk2(float lo, float hi) {
    return (unsigned int)f2b(lo) | ((unsigned int)f2b(hi) << 16);
}

// ---------------------------------------------------------------------------
// Kernel 1: QKV = X(4096x2048 fp32) * W^T + bias. bf16 MFMA, fp32 staged->bf16.
// q,k stored [B][NH][S][HD]; V stored TRANSPOSED [B][NH][HD][S] so the
// attention kernel can stage Vt tiles with vector loads.
// ---------------------------------------------------------------------------
__global__ __launch_bounds__(256, 2) void qkv_gemm(
    const float* __restrict__ X,
    const float* __restrict__ W,
    const float* __restrict__ bias,
    unsigned short* __restrict__ qb,
    unsigned short* __restrict__ kb,
    unsigned short* __restrict__ vb)
{
    __shared__ __align__(16) unsigned short As[128 * 32];
    __shared__ __align__(16) unsigned short Bs[128 * 32];

    const int t    = threadIdx.x;
    const int lane = t & 63;
    const int wave = t >> 6;
    const int m0   = blockIdx.y * 128;
    const int n0   = blockIdx.x * 128;
    const int wm   = (wave >> 1) * 64;
    const int wn   = (wave & 1) * 64;
    const int quad = lane >> 4;
    const int l16  = lane & 15;

    const int srow = t >> 2;          // 0..63
    const int scol = (t & 3) * 8;     // 0,8,16,24

    const float* Ap = X + (m0 + srow) * E_ + scol;
    const float* Bp = W + (n0 + srow) * E_ + scol;

    f32x4 acc[4][4];
    #pragma unroll
    for (int i = 0; i < 4; i++)
        #pragma unroll
        for (int j = 0; j < 4; j++)
            #pragma unroll
            for (int r = 0; r < 4; r++) acc[i][j][r] = 0.0f;

    for (int k0 = 0; k0 < E_; k0 += 32) {
        float4 a00 = *(const float4*)(Ap + k0);
        float4 a01 = *(const float4*)(Ap + k0 + 4);
        float4 a10 = *(const float4*)(Ap + k0 + 64 * E_);
        float4 a11 = *(const float4*)(Ap + k0 + 64 * E_ + 4);
        float4 b00 = *(const float4*)(Bp + k0);
        float4 b01 = *(const float4*)(Bp + k0 + 4);
        float4 b10 = *(const float4*)(Bp + k0 + 64 * E_);
        float4 b11 = *(const float4*)(Bp + k0 + 64 * E_ + 4);
        __syncthreads();
        {
            uint4 pa0 = { pk2(a00.x, a00.y), pk2(a00.z, a00.w),
                          pk2(a01.x, a01.y), pk2(a01.z, a01.w) };
            uint4 pa1 = { pk2(a10.x, a10.y), pk2(a10.z, a10.w),
                          pk2(a11.x, a11.y), pk2(a11.z, a11.w) };
            uint4 pb0 = { pk2(b00.x, b00.y), pk2(b00.z, b00.w),
                          pk2(b01.x, b01.y), pk2(b01.z, b01.w) };
            uint4 pb1 = { pk2(b10.x, b10.y), pk2(b10.z, b10.w),
                          pk2(b11.x, b11.y), pk2(b11.z, b11.w) };
            *(uint4*)&As[srow * 32 + scol]        = pa0;
            *(uint4*)&As[(srow + 64) * 32 + scol] = pa1;
            *(uint4*)&Bs[srow * 32 + scol]        = pb0;
            *(uint4*)&Bs[(srow + 64) * 32 + scol] = pb1;
        }
        __syncthreads();

        bf16x8 af[4], bfr[4];
        #pragma unroll
        for (int i = 0; i < 4; i++)
            af[i]  = *(const bf16x8*)&As[(wm + i * 16 + l16) * 32 + quad * 8];
        #pragma unroll
        for (int i = 0; i < 4; i++)
            bfr[i] = *(const bf16x8*)&Bs[(wn + i * 16 + l16) * 32 + quad * 8];

        #pragma unroll
        for (int i = 0; i < 4; i++)
            #pragma unroll
            for (int j = 0; j < 4; j++)
                acc[i][j] = __builtin_amdgcn_mfma_f32_16x16x32_bf16(
                    af[i], bfr[j], acc[i][j], 0, 0, 0);
    }

    // epilogue: bias + scatter. q/k -> [B][NH][S][HD]; v -> [B][NH][HD][S]
    #pragma unroll
    for (int j = 0; j < 4; j++) {
        const int n = n0 + wn + j * 16 + l16;           // 0..6143
        const float bv = bias[n];
        const int which = n >> 11;                      // 0=q 1=k 2=v
        const int h = (n >> 7) & 15;
        const int d = n & 127;
        unsigned short* dst = (which == 0) ? qb : ((which == 1) ? kb : vb);
        #pragma unroll
        for (int i = 0; i < 4; i++) {
            #pragma unroll
            for (int r = 0; r < 4; r++) {
                const int m  = m0 + wm + i * 16 + quad * 4 + r;  // 0..4095
                const int bb = m >> 11;
                const int s  = m & (S_ - 1);
                const size_t idx = (which == 2)
                    ? (((size_t)(bb * NH_ + h) * HD_ + d) * S_ + s)
                    : (((size_t)(bb * NH_ + h) * S_ + s) * HD_ + d);
                dst[idx] = f2b(acc[i][j][r] + bv);
            }
        }
    }
}

// ---------------------------------------------------------------------------
// Kernel 2: in-place RoPE on q and k (bf16, fp32 math). Layout [B][NH][S][HD].
// ---------------------------------------------------------------------------
__global__ void rope_inplace(unsigned short* __restrict__ qb,
                             unsigned short* __restrict__ kb)
{
    const int idx = blockIdx.x * 256 + threadIdx.x;     // B*NH*S*16 exactly
    const int i   = idx & 15;
    const int s   = (idx >> 4) & (S_ - 1);
    const int bh  = idx >> 15;
    const float inv = exp2f(-0.83048202372184059f * (float)i); // log2(1e4)/16
    const float ang = (float)s * inv;
    const float c  = cosf(ang);
    const float sn = sinf(ang);
    const int base = (bh * S_ + s) * HD_;
    {
        float u1 = b2f(qb[base + i]), u2 = b2f(qb[base + i + 16]);
        qb[base + i]      = f2b(u1 * c - u2 * sn);
        qb[base + i + 16] = f2b(u1 * sn + u2 * c);
    }
    {
        float u1 = b2f(kb[base + i]), u2 = b2f(kb[base + i + 16]);
        kb[base + i]      = f2b(u1 * c - u2 * sn);
        kb[base + i + 16] = f2b(u1 * sn + u2 * c);
    }
}

// ---------------------------------------------------------------------------
// Kernel 3: MFMA causal flash attention.
// Block = 256 thr = 4 waves; block owns 64 q-rows (wave w: rows qt*64+w*16+..).
// K-tile = 64. Layouts (HW-verified 16x16x32_bf16):
//   A-frag  A[m=lane&15][k=quad*8+j]     C/D: row=quad*4+reg, col=lane&15
// QK^T: Q A-frags from global, K B-frags from LDS Ks[64][136] (pad: 2-way free)
// P: C-layout -> LDS (wave-private, [16][72]) -> A-frags (b128)
// PV: Vt B-frags from LDS Vt[128][72], staged from global V^T [B][NH][HD][S].
// Online softmax per row in fp32; -1e4 additive mask = reference NEG_INF.
// ---------------------------------------------------------------------------
#define KSTR 136
#define VSTR 72
#define PSTR 72

__global__ __launch_bounds__(256, 2) void attn_mfma(
    const unsigned short* __restrict__ qb,
    const unsigned short* __restrict__ kb,
    const unsigned short* __restrict__ vb,
    float* __restrict__ out)
{
    __shared__ __align__(16) unsigned short Ks[64 * KSTR];    // 17408 B
    __shared__ __align__(16) unsigned short Vt[128 * VSTR];   // 18432 B
    __shared__ __align__(16) unsigned short Ps[4 * 16 * PSTR];//  9216 B

    const int qt   = (int)gridDim.x - 1 - (int)blockIdx.x;    // heavy first
    const int bh   = blockIdx.y;
    const int b    = bh >> 4;
    const int h    = bh & 15;
    const int t    = threadIdx.x;
    const int lane = t & 63;
    const int w    = t >> 6;
    const int quad = lane >> 4;
    const int l16  = lane & 15;

    unsigned short* Pw = Ps + w * 16 * PSTR;

    // Q A-fragments straight from global: m = l16, k = c*32 + quad*8 + j
    bf16x8 qf[4];
    {
        const unsigned short* qp =
            qb + ((size_t)(bh * S_ + qt * 64 + w * 16 + l16)) * HD_ + quad * 8;
        #pragma unroll
        for (int c = 0; c < 4; c++)
            qf[c] = *(const bf16x8*)(qp + c * 32);
    }

    f32x4 of[8];
    #pragma unroll
    for (int db = 0; db < 8; db++)
        #pragma unroll
        for (int r = 0; r < 4; r++) of[db][r] = 0.0f;
    float mr[4], lr[4];
    #pragma unroll
    for (int r = 0; r < 4; r++) { mr[r] = -1e30f; lr[r] = 0.0f; }

    const float scale = 0.088388347648318447f;  // 1/sqrt(128)
    const int   qr0   = qt * 64 + w * 16 + quad * 4;  // this lane's first C-row

    for (int kt = 0; kt <= qt; kt++) {
        const int s0 = kt * 64;
        // ---- stage K[64][128] and Vt[128][64] (regs first: overlap compute)
        const int krow = t >> 2, kcb = (t & 3) * 32;
        const int vrow = t >> 1, vcb = (t & 1) * 32;
        uint4 kv[4], vv[4];
        {
            const unsigned short* kg =
                kb + ((size_t)(bh * S_ + s0 + krow)) * HD_ + kcb;
            const unsigned short* vg =
                vb + ((size_t)(bh * HD_ + vrow)) * S_ + s0 + vcb;
            #pragma unroll
            for (int u = 0; u < 4; u++) kv[u] = *(const uint4*)(kg + u * 8);
            #pragma unroll
            for (int u = 0; u < 4; u++) vv[u] = *(const uint4*)(vg + u * 8);
        }
        __syncthreads();                      // prior iter's readers done
        #pragma unroll
        for (int u = 0; u < 4; u++) *(uint4*)&Ks[krow * KSTR + kcb + u * 8] = kv[u];
        #pragma unroll
        for (int u = 0; u < 4; u++) *(uint4*)&Vt[vrow * VSTR + vcb + u * 8] = vv[u];
        __syncthreads();

        // ---- S = Q K^T  (rows qr0..qr0+3, cols s0 + nb*16 + l16)
        f32x4 sf[4];
        #pragma unroll
        for (int nb = 0; nb < 4; nb++)
            #pragma unroll
            for (int r = 0; r < 4; r++) sf[nb][r] = 0.0f;
        #pragma unroll
        for (int c = 0; c < 4; c++) {
            #pragma unroll
            for (int nb = 0; nb < 4; nb++) {
                bf16x8 kf = *(const bf16x8*)&Ks[(nb * 16 + l16) * KSTR + c * 32 + quad * 8];
                sf[nb] = __builtin_amdgcn_mfma_f32_16x16x32_bf16(qf[c], kf, sf[nb], 0, 0, 0);
            }
        }

        // ---- scale + causal mask (diagonal tile only)
        const bool diag = (kt == qt);
        #pragma unroll
        for (int nb = 0; nb < 4; nb++) {
            const int kcol = s0 + nb * 16 + l16;
            #pragma unroll
            for (int r = 0; r < 4; r++) {
                float s = sf[nb][r] * scale;
                if (diag && kcol > qr0 + r) s += -10000.0f;
                sf[nb][r] = s;
            }
        }

        // ---- online softmax (row = qr0+r; reduce over 16-lane col group)
        float alpha[4];
        #pragma unroll
        for (int r = 0; r < 4; r++) {
            float mt = fmaxf(fmaxf(sf[0][r], sf[1][r]), fmaxf(sf[2][r], sf[3][r]));
            mt = fmaxf(mt, __shfl_xor(mt, 1));
            mt = fmaxf(mt, __shfl_xor(mt, 2));
            mt = fmaxf(mt, __shfl_xor(mt, 4));
            mt = fmaxf(mt, __shfl_xor(mt, 8));
            const float mnew = fmaxf(mr[r], mt);
            alpha[r] = __expf(mr[r] - mnew);
            mr[r] = mnew;
        }
        #pragma unroll
        for (int r = 0; r < 4; r++) {
            float rs = 0.0f;
            #pragma unroll
            for (int nb = 0; nb < 4; nb++) {
                float p = __expf(sf[nb][r] - mr[r]);
                sf[nb][r] = p;
                rs += p;
            }
            rs += __shfl_xor(rs, 1);
            rs += __shfl_xor(rs, 2);
            rs += __shfl_xor(rs, 4);
            rs += __shfl_xor(rs, 8);
            lr[r] = lr[r] * alpha[r] + rs;
        }
        #pragma unroll
        for (int db = 0; db < 8; db++)
            #pragma unroll
            for (int r = 0; r < 4; r++) of[db][r] *= alpha[r];

        // ---- P: C-layout -> wave-private LDS [m][s] (scalar u16 writes)
        #pragma unroll
        for (int nb = 0; nb < 4; nb++)
            #pragma unroll
            for (int r = 0; r < 4; r++)
                Pw[(quad * 4 + r) * PSTR + nb * 16 + l16] = f2b(sf[nb][r]);
        // (compiler inserts lgkmcnt wait for the LDS RAW dependency below)

        // ---- O += P V   (A = P[m=l16][k], B = Vt[n=d=l16][k=s])
        #pragma unroll
        for (int kc = 0; kc < 2; kc++) {
            bf16x8 pf = *(const bf16x8*)&Pw[l16 * PSTR + kc * 32 + quad * 8];
            #pragma unroll
            for (int db = 0; db < 8; db++) {
                bf16x8 vf = *(const bf16x8*)&Vt[(db * 16 + l16) * VSTR + kc * 32 + quad * 8];
                of[db] = __builtin_amdgcn_mfma_f32_16x16x32_bf16(pf, vf, of[db], 0, 0, 0);
            }
        }
    }

    // ---- normalize + store fp32 (row qr0+r, col h*128 + db*16 + l16)
    #pragma unroll
    for (int r = 0; r < 4; r++) {
        const float inv = 1.0f / lr[r];
        float* op = out + ((size_t)(b * S_ + qr0 + r)) * E_ + h * HD_ + l16;
        #pragma unroll
        for (int db = 0; db < 8; db++)
            op[db * 16] = of[db][r] * inv;
    }
}

// ---------------------------------------------------------------------------
extern "C" void kernel_launch(void* const* d_in, const int* in_sizes, int n_in,
                              void* d_out, int out_size, void* d_ws, size_t ws_size,
                              hipStream_t stream)
{
    const float* x    = (const float*)d_in[0];   // fp32 (B,S,E)
    const float* W    = (const float*)d_in[1];   // fp32 (6144,2048)
    const float* bias = (const float*)d_in[2];   // fp32 (6144,)
    float* out = (float*)d_out;                  // fp32 (B,S,E)

    const size_t per = (size_t)B_ * NH_ * S_ * HD_;               // 8388608
    unsigned short* qb = (unsigned short*)d_ws;                   // [B][NH][S][HD]
    unsigned short* kb = qb + per;                                // [B][NH][S][HD]
    unsigned short* vb = kb + per;                                // [B][NH][HD][S]

    dim3 gemm_grid(NQKV_ / 128, M_ / 128);                        // 48 x 32
    qkv_gemm<<<gemm_grid, 256, 0, stream>>>(x, W, bias, qb, kb, vb);

    rope_inplace<<<(B_ * NH_ * S_ * 16) / 256, 256, 0, stream>>>(qb, kb);

    dim3 attn_grid(S_ / 64, B_ * NH_);                            // 32 x 32
    attn_mfma<<<attn_grid, 256, 0, stream>>>(qb, kb, vb, out);
}

// Round 4
// 533.388 us; speedup vs baseline: 5.0676x; 1.1403x over previous
//
#include <hip/hip_runtime.h>

// MHA: QKV GEMM (fp32 in, bf16 MFMA) -> RoPE -> MFMA flash attention (fp32 out)
// B=2 S=2048 E=2048 NH=16 HD=128 ROTARY=32 base=1e4 NEG_INF=-1e4
#define B_    2
#define S_    2048
#define E_    2048
#define NH_   16
#define HD_   128
#define NQKV_ 6144
#define M_    4096

typedef short bf16x8 __attribute__((ext_vector_type(8)));   // 8 bf16 (4 VGPRs)
typedef float f32x4  __attribute__((ext_vector_type(4)));   // MFMA C/D

__device__ inline float b2f(unsigned short u) {
    return __uint_as_float(((unsigned int)u) << 16);
}
__device__ inline unsigned short f2b(float f) {             // RNE f32->bf16
    unsigned int x = __float_as_uint(f);
    x = x + 0x7fffu + ((x >> 16) & 1u);
    return (unsigned short)(x >> 16);
}
__device__ inline unsigned int pk2(float lo, float hi) {
    return (unsigned int)f2b(lo) | ((unsigned int)f2b(hi) << 16);
}

// ---------------------------------------------------------------------------
// Kernel 1: QKV = X(4096x2048 fp32) * W^T + bias. bf16 MFMA.
// Round-4: software prefetch (loads for k0+32 issued before MFMA on k0);
// epilogue reverted to round-2 (ALL of q/k/v row-major [B][NH][S][HD] —
// the V-transpose scatter caused massive write amplification).
// ---------------------------------------------------------------------------
__global__ __launch_bounds__(256, 2) void qkv_gemm(
    const float* __restrict__ X,
    const float* __restrict__ W,
    const float* __restrict__ bias,
    unsigned short* __restrict__ qb,
    unsigned short* __restrict__ kb,
    unsigned short* __restrict__ vb)
{
    __shared__ __align__(16) unsigned short As[128 * 32];
    __shared__ __align__(16) unsigned short Bs[128 * 32];

    const int t    = threadIdx.x;
    const int lane = t & 63;
    const int wave = t >> 6;
    const int m0   = blockIdx.y * 128;
    const int n0   = blockIdx.x * 128;
    const int wm   = (wave >> 1) * 64;
    const int wn   = (wave & 1) * 64;
    const int quad = lane >> 4;
    const int l16  = lane & 15;

    const int srow = t >> 2;          // 0..63
    const int scol = (t & 3) * 8;     // 0,8,16,24

    const float* Ap = X + (m0 + srow) * E_ + scol;
    const float* Bp = W + (n0 + srow) * E_ + scol;

    f32x4 acc[4][4];
    #pragma unroll
    for (int i = 0; i < 4; i++)
        #pragma unroll
        for (int j = 0; j < 4; j++)
            #pragma unroll
            for (int r = 0; r < 4; r++) acc[i][j][r] = 0.0f;

    // prefetch tile k0=0
    float4 a00 = *(const float4*)(Ap);
    float4 a01 = *(const float4*)(Ap + 4);
    float4 a10 = *(const float4*)(Ap + 64 * E_);
    float4 a11 = *(const float4*)(Ap + 64 * E_ + 4);
    float4 b00 = *(const float4*)(Bp);
    float4 b01 = *(const float4*)(Bp + 4);
    float4 b10 = *(const float4*)(Bp + 64 * E_);
    float4 b11 = *(const float4*)(Bp + 64 * E_ + 4);

    for (int k0 = 0; k0 < E_; k0 += 32) {
        __syncthreads();
        {
            uint4 pa0 = { pk2(a00.x, a00.y), pk2(a00.z, a00.w),
                          pk2(a01.x, a01.y), pk2(a01.z, a01.w) };
            uint4 pa1 = { pk2(a10.x, a10.y), pk2(a10.z, a10.w),
                          pk2(a11.x, a11.y), pk2(a11.z, a11.w) };
            uint4 pb0 = { pk2(b00.x, b00.y), pk2(b00.z, b00.w),
                          pk2(b01.x, b01.y), pk2(b01.z, b01.w) };
            uint4 pb1 = { pk2(b10.x, b10.y), pk2(b10.z, b10.w),
                          pk2(b11.x, b11.y), pk2(b11.z, b11.w) };
            *(uint4*)&As[srow * 32 + scol]        = pa0;
            *(uint4*)&As[(srow + 64) * 32 + scol] = pa1;
            *(uint4*)&Bs[srow * 32 + scol]        = pb0;
            *(uint4*)&Bs[(srow + 64) * 32 + scol] = pb1;
        }
        __syncthreads();

        // prefetch NEXT tile while this tile's MFMAs run
        const int kn = k0 + 32;
        if (kn < E_) {
            a00 = *(const float4*)(Ap + kn);
            a01 = *(const float4*)(Ap + kn + 4);
            a10 = *(const float4*)(Ap + kn + 64 * E_);
            a11 = *(const float4*)(Ap + kn + 64 * E_ + 4);
            b00 = *(const float4*)(Bp + kn);
            b01 = *(const float4*)(Bp + kn + 4);
            b10 = *(const float4*)(Bp + kn + 64 * E_);
            b11 = *(const float4*)(Bp + kn + 64 * E_ + 4);
        }

        bf16x8 af[4], bfr[4];
        #pragma unroll
        for (int i = 0; i < 4; i++)
            af[i]  = *(const bf16x8*)&As[(wm + i * 16 + l16) * 32 + quad * 8];
        #pragma unroll
        for (int i = 0; i < 4; i++)
            bfr[i] = *(const bf16x8*)&Bs[(wn + i * 16 + l16) * 32 + quad * 8];

        #pragma unroll
        for (int i = 0; i < 4; i++)
            #pragma unroll
            for (int j = 0; j < 4; j++)
                acc[i][j] = __builtin_amdgcn_mfma_f32_16x16x32_bf16(
                    af[i], bfr[j], acc[i][j], 0, 0, 0);
    }

    // epilogue: bias + scatter. q/k/v all row-major [B][NH][S][HD]
    #pragma unroll
    for (int j = 0; j < 4; j++) {
        const int n = n0 + wn + j * 16 + l16;           // 0..6143
        const float bv = bias[n];
        const int which = n >> 11;                      // 0=q 1=k 2=v
        const int h = (n >> 7) & 15;
        const int d = n & 127;
        unsigned short* dst = (which == 0) ? qb : ((which == 1) ? kb : vb);
        #pragma unroll
        for (int i = 0; i < 4; i++) {
            #pragma unroll
            for (int r = 0; r < 4; r++) {
                const int m  = m0 + wm + i * 16 + quad * 4 + r;  // 0..4095
                const int bb = m >> 11;
                const int s  = m & (S_ - 1);
                dst[((size_t)(bb * NH_ + h) * S_ + s) * HD_ + d] = f2b(acc[i][j][r] + bv);
            }
        }
    }
}

// ---------------------------------------------------------------------------
// Kernel 2: in-place RoPE on q and k (bf16, fp32 math). Layout [B][NH][S][HD].
// ---------------------------------------------------------------------------
__global__ void rope_inplace(unsigned short* __restrict__ qb,
                             unsigned short* __restrict__ kb)
{
    const int idx = blockIdx.x * 256 + threadIdx.x;     // B*NH*S*16 exactly
    const int i   = idx & 15;
    const int s   = (idx >> 4) & (S_ - 1);
    const int bh  = idx >> 15;
    const float inv = exp2f(-0.83048202372184059f * (float)i); // log2(1e4)/16
    const float ang = (float)s * inv;
    const float c  = cosf(ang);
    const float sn = sinf(ang);
    const int base = (bh * S_ + s) * HD_;
    {
        float u1 = b2f(qb[base + i]), u2 = b2f(qb[base + i + 16]);
        qb[base + i]      = f2b(u1 * c - u2 * sn);
        qb[base + i + 16] = f2b(u1 * sn + u2 * c);
    }
    {
        float u1 = b2f(kb[base + i]), u2 = b2f(kb[base + i + 16]);
        kb[base + i]      = f2b(u1 * c - u2 * sn);
        kb[base + i + 16] = f2b(u1 * sn + u2 * c);
    }
}

// ---------------------------------------------------------------------------
// Kernel 3: MFMA causal flash attention. Round-4 changes:
//  * V read row-major [B][NH][S][HD], transposed into LDS Vt during staging
//    (s-pair packed ds_write_b32; lane->bank analysis: 32 banks, 2/bank, free)
//  * software prefetch: global loads for tile kt+1 issued before compute(kt)
//  * O epilogue: AGPR->LDS transpose -> float4 coalesced stores (kills the
//    8x write amplification seen in round 3's scalar stores)
// Layouts (HW-verified 16x16x32_bf16): A[m=lane&15][k=quad*8+j];
// C/D row=quad*4+reg, col=lane&15.
// ---------------------------------------------------------------------------
#define KSTR 136
#define VSTR 72
#define PSTR 72
#define OSTR 132

__global__ __launch_bounds__(256, 2) void attn_mfma(
    const unsigned short* __restrict__ qb,
    const unsigned short* __restrict__ kb,
    const unsigned short* __restrict__ vb,
    float* __restrict__ out)
{
    union SM {
        struct {
            unsigned short Ks[64 * KSTR];     // 17408 B
            unsigned short Vt[128 * VSTR];    // 18432 B
            unsigned short Ps[4 * 16 * PSTR]; //  9216 B
        } a;
        float Ow[4 * 16 * OSTR];              // 33792 B (reused in epilogue)
    };
    __shared__ __align__(16) SM sm;
    unsigned short* Ks = sm.a.Ks;
    unsigned short* Vt = sm.a.Vt;
    unsigned short* Ps = sm.a.Ps;

    const int qt   = (int)gridDim.x - 1 - (int)blockIdx.x;    // heavy first
    const int bh   = blockIdx.y;
    const int b    = bh >> 4;
    const int h    = bh & 15;
    const int t    = threadIdx.x;
    const int lane = t & 63;
    const int w    = t >> 6;
    const int quad = lane >> 4;
    const int l16  = lane & 15;

    unsigned short* Pw = Ps + w * 16 * PSTR;

    // staging maps
    const int krow = t >> 2, kcb = (t & 3) * 32;   // K: row, col-block
    const int vq   = t & 31, vd0 = (t >> 5) * 16;  // V: s-pair, d-block

    // Q A-fragments straight from global: m = l16, k = c*32 + quad*8 + j
    bf16x8 qf[4];
    {
        const unsigned short* qp =
            qb + ((size_t)(bh * S_ + qt * 64 + w * 16 + l16)) * HD_ + quad * 8;
        #pragma unroll
        for (int c = 0; c < 4; c++)
            qf[c] = *(const bf16x8*)(qp + c * 32);
    }

    f32x4 of[8];
    #pragma unroll
    for (int db = 0; db < 8; db++)
        #pragma unroll
        for (int r = 0; r < 4; r++) of[db][r] = 0.0f;
    float mr[4], lr[4];
    #pragma unroll
    for (int r = 0; r < 4; r++) { mr[r] = -1e30f; lr[r] = 0.0f; }

    const float scale = 0.088388347648318447f;        // 1/sqrt(128)
    const int   qr0   = qt * 64 + w * 16 + quad * 4;  // this lane's first C-row

    // prefetch registers
    uint4 kr[4];
    uint4 v0a, v0b, v1a, v1b;

    // issue global loads for K/V tile kt2 (no waits here)
    auto issue_tile = [&](int kt2) {
        const int s2 = kt2 * 64;
        const unsigned short* kg = kb + ((size_t)(bh * S_ + s2 + krow)) * HD_ + kcb;
        #pragma unroll
        for (int u = 0; u < 4; u++) kr[u] = *(const uint4*)(kg + u * 8);
        const unsigned short* vg = vb + ((size_t)(bh * S_ + s2 + 2 * vq)) * HD_ + vd0;
        v0a = *(const uint4*)(vg);
        v0b = *(const uint4*)(vg + 8);
        v1a = *(const uint4*)(vg + HD_);
        v1b = *(const uint4*)(vg + HD_ + 8);
    };

    issue_tile(0);

    for (int kt = 0; kt <= qt; kt++) {
        const int s0 = kt * 64;
        __syncthreads();                  // prior iter's LDS readers done
        // ---- K tile -> LDS (row-major, b128)
        #pragma unroll
        for (int u = 0; u < 4; u++)
            *(uint4*)&Ks[krow * KSTR + kcb + u * 8] = kr[u];
        // ---- V tile -> LDS transposed: Vt[d][s], s-pairs packed as b32
        {
            unsigned int r0[8] = { v0a.x, v0a.y, v0a.z, v0a.w,
                                   v0b.x, v0b.y, v0b.z, v0b.w };
            unsigned int r1[8] = { v1a.x, v1a.y, v1a.z, v1a.w,
                                   v1b.x, v1b.y, v1b.z, v1b.w };
            #pragma unroll
            for (int j = 0; j < 16; j++) {
                const int u = j >> 1;
                unsigned int pk;
                if ((j & 1) == 0)
                    pk = (r0[u] & 0xffffu) | (r1[u] << 16);
                else
                    pk = (r0[u] >> 16) | (r1[u] & 0xffff0000u);
                *(unsigned int*)&Vt[(vd0 + j) * VSTR + 2 * vq] = pk;
            }
        }
        __syncthreads();

        // ---- prefetch next tile while computing this one
        if (kt < qt) issue_tile(kt + 1);

        // ---- S = Q K^T  (rows qr0..qr0+3, cols s0 + nb*16 + l16)
        f32x4 sf[4];
        #pragma unroll
        for (int nb = 0; nb < 4; nb++)
            #pragma unroll
            for (int r = 0; r < 4; r++) sf[nb][r] = 0.0f;
        #pragma unroll
        for (int c = 0; c < 4; c++) {
            #pragma unroll
            for (int nb = 0; nb < 4; nb++) {
                bf16x8 kf = *(const bf16x8*)&Ks[(nb * 16 + l16) * KSTR + c * 32 + quad * 8];
                sf[nb] = __builtin_amdgcn_mfma_f32_16x16x32_bf16(qf[c], kf, sf[nb], 0, 0, 0);
            }
        }

        // ---- scale + causal mask (diagonal tile only)
        const bool diag = (kt == qt);
        #pragma unroll
        for (int nb = 0; nb < 4; nb++) {
            const int kcol = s0 + nb * 16 + l16;
            #pragma unroll
            for (int r = 0; r < 4; r++) {
                float s = sf[nb][r] * scale;
                if (diag && kcol > qr0 + r) s += -10000.0f;
                sf[nb][r] = s;
            }
        }

        // ---- online softmax (row = qr0+r; reduce over 16-lane col group)
        float alpha[4];
        #pragma unroll
        for (int r = 0; r < 4; r++) {
            float mt = fmaxf(fmaxf(sf[0][r], sf[1][r]), fmaxf(sf[2][r], sf[3][r]));
            mt = fmaxf(mt, __shfl_xor(mt, 1));
            mt = fmaxf(mt, __shfl_xor(mt, 2));
            mt = fmaxf(mt, __shfl_xor(mt, 4));
            mt = fmaxf(mt, __shfl_xor(mt, 8));
            const float mnew = fmaxf(mr[r], mt);
            alpha[r] = __expf(mr[r] - mnew);
            mr[r] = mnew;
        }
        #pragma unroll
        for (int r = 0; r < 4; r++) {
            float rs = 0.0f;
            #pragma unroll
            for (int nb = 0; nb < 4; nb++) {
                float p = __expf(sf[nb][r] - mr[r]);
                sf[nb][r] = p;
                rs += p;
            }
            rs += __shfl_xor(rs, 1);
            rs += __shfl_xor(rs, 2);
            rs += __shfl_xor(rs, 4);
            rs += __shfl_xor(rs, 8);
            lr[r] = lr[r] * alpha[r] + rs;
        }
        #pragma unroll
        for (int db = 0; db < 8; db++)
            #pragma unroll
            for (int r = 0; r < 4; r++) of[db][r] *= alpha[r];

        // ---- P: C-layout -> wave-private LDS [m][s] (scalar u16 writes)
        #pragma unroll
        for (int nb = 0; nb < 4; nb++)
            #pragma unroll
            for (int r = 0; r < 4; r++)
                Pw[(quad * 4 + r) * PSTR + nb * 16 + l16] = f2b(sf[nb][r]);

        // ---- O += P V   (A = P[m=l16][k], B = Vt[n=d=l16][k=s])
        #pragma unroll
        for (int kc = 0; kc < 2; kc++) {
            bf16x8 pf = *(const bf16x8*)&Pw[l16 * PSTR + kc * 32 + quad * 8];
            #pragma unroll
            for (int db = 0; db < 8; db++) {
                bf16x8 vf = *(const bf16x8*)&Vt[(db * 16 + l16) * VSTR + kc * 32 + quad * 8];
                of[db] = __builtin_amdgcn_mfma_f32_16x16x32_bf16(pf, vf, of[db], 0, 0, 0);
            }
        }
    }

    // ---- epilogue: normalize, transpose via LDS, coalesced float4 stores
    __syncthreads();                       // all waves done reading Ks/Vt/Ps
    float* Ow = sm.Ow + w * 16 * OSTR;     // wave-private 16x132 fp32
    float inv[4];
    #pragma unroll
    for (int r = 0; r < 4; r++) inv[r] = 1.0f / lr[r];
    #pragma unroll
    for (int db = 0; db < 8; db++)
        #pragma unroll
        for (int r = 0; r < 4; r++)
            Ow[(quad * 4 + r) * OSTR + db * 16 + l16] = of[db][r] * inv[r];
    // wave-private: compiler inserts the lgkmcnt wait for the RAW below
    #pragma unroll
    for (int rg = 0; rg < 4; rg++) {
        const int rowl = rg * 4 + quad;
        float* op = out + ((size_t)(b * S_ + qt * 64 + w * 16 + rowl)) * E_ + h * HD_;
        #pragma unroll
        for (int u = 0; u < 2; u++) {
            float4 v4 = *(const float4*)&Ow[rowl * OSTR + u * 64 + l16 * 4];
            *(float4*)(op + u * 64 + l16 * 4) = v4;
        }
    }
}

// ---------------------------------------------------------------------------
extern "C" void kernel_launch(void* const* d_in, const int* in_sizes, int n_in,
                              void* d_out, int out_size, void* d_ws, size_t ws_size,
                              hipStream_t stream)
{
    const float* x    = (const float*)d_in[0];   // fp32 (B,S,E)
    const float* W    = (const float*)d_in[1];   // fp32 (6144,2048)
    const float* bias = (const float*)d_in[2];   // fp32 (6144,)
    float* out = (float*)d_out;                  // fp32 (B,S,E)

    const size_t per = (size_t)B_ * NH_ * S_ * HD_;               // 8388608
    unsigned short* qb = (unsigned short*)d_ws;                   // [B][NH][S][HD]
    unsigned short* kb = qb + per;                                // [B][NH][S][HD]
    unsigned short* vb = kb + per;                                // [B][NH][S][HD]

    dim3 gemm_grid(NQKV_ / 128, M_ / 128);                        // 48 x 32
    qkv_gemm<<<gemm_grid, 256, 0, stream>>>(x, W, bias, qb, kb, vb);

    rope_inplace<<<(B_ * NH_ * S_ * 16) / 256, 256, 0, stream>>>(qb, kb);

    dim3 attn_grid(S_ / 64, B_ * NH_);                            // 32 x 32
    attn_mfma<<<attn_grid, 256, 0, stream>>>(qb, kb, vb, out);
}

// Round 5
// 482.727 us; speedup vs baseline: 5.5994x; 1.1049x over previous
//
#include <hip/hip_runtime.h>

// MHA: QKV GEMM (fp32 in, bf16 MFMA) -> RoPE -> MFMA flash attention (fp32 out)
// B=2 S=2048 E=2048 NH=16 HD=128 ROTARY=32 base=1e4 NEG_INF=-1e4
#define B_    2
#define S_    2048
#define E_    2048
#define NH_   16
#define HD_   128
#define NQKV_ 6144
#define M_    4096

typedef short bf16x8 __attribute__((ext_vector_type(8)));   // 8 bf16 (4 VGPRs)
typedef float f32x4  __attribute__((ext_vector_type(4)));   // MFMA C/D

__device__ inline float b2f(unsigned short u) {
    return __uint_as_float(((unsigned int)u) << 16);
}
__device__ inline unsigned short f2b(float f) {             // RNE f32->bf16
    unsigned int x = __float_as_uint(f);
    x = x + 0x7fffu + ((x >> 16) & 1u);
    return (unsigned short)(x >> 16);
}
__device__ inline unsigned int pk2(float lo, float hi) {
    return (unsigned int)f2b(lo) | ((unsigned int)f2b(hi) << 16);
}

// ---------------------------------------------------------------------------
// Kernel 1: QKV = X(4096x2048 fp32) * W^T + bias. bf16 MFMA, reg prefetch.
// q/k/v all row-major [B][NH][S][HD]. (unchanged from round 4)
// ---------------------------------------------------------------------------
__global__ __launch_bounds__(256, 2) void qkv_gemm(
    const float* __restrict__ X,
    const float* __restrict__ W,
    const float* __restrict__ bias,
    unsigned short* __restrict__ qb,
    unsigned short* __restrict__ kb,
    unsigned short* __restrict__ vb)
{
    __shared__ __align__(16) unsigned short As[128 * 32];
    __shared__ __align__(16) unsigned short Bs[128 * 32];

    const int t    = threadIdx.x;
    const int lane = t & 63;
    const int wave = t >> 6;
    const int m0   = blockIdx.y * 128;
    const int n0   = blockIdx.x * 128;
    const int wm   = (wave >> 1) * 64;
    const int wn   = (wave & 1) * 64;
    const int quad = lane >> 4;
    const int l16  = lane & 15;

    const int srow = t >> 2;          // 0..63
    const int scol = (t & 3) * 8;     // 0,8,16,24

    const float* Ap = X + (m0 + srow) * E_ + scol;
    const float* Bp = W + (n0 + srow) * E_ + scol;

    f32x4 acc[4][4];
    #pragma unroll
    for (int i = 0; i < 4; i++)
        #pragma unroll
        for (int j = 0; j < 4; j++)
            #pragma unroll
            for (int r = 0; r < 4; r++) acc[i][j][r] = 0.0f;

    float4 a00 = *(const float4*)(Ap);
    float4 a01 = *(const float4*)(Ap + 4);
    float4 a10 = *(const float4*)(Ap + 64 * E_);
    float4 a11 = *(const float4*)(Ap + 64 * E_ + 4);
    float4 b00 = *(const float4*)(Bp);
    float4 b01 = *(const float4*)(Bp + 4);
    float4 b10 = *(const float4*)(Bp + 64 * E_);
    float4 b11 = *(const float4*)(Bp + 64 * E_ + 4);

    for (int k0 = 0; k0 < E_; k0 += 32) {
        __syncthreads();
        {
            uint4 pa0 = { pk2(a00.x, a00.y), pk2(a00.z, a00.w),
                          pk2(a01.x, a01.y), pk2(a01.z, a01.w) };
            uint4 pa1 = { pk2(a10.x, a10.y), pk2(a10.z, a10.w),
                          pk2(a11.x, a11.y), pk2(a11.z, a11.w) };
            uint4 pb0 = { pk2(b00.x, b00.y), pk2(b00.z, b00.w),
                          pk2(b01.x, b01.y), pk2(b01.z, b01.w) };
            uint4 pb1 = { pk2(b10.x, b10.y), pk2(b10.z, b10.w),
                          pk2(b11.x, b11.y), pk2(b11.z, b11.w) };
            *(uint4*)&As[srow * 32 + scol]        = pa0;
            *(uint4*)&As[(srow + 64) * 32 + scol] = pa1;
            *(uint4*)&Bs[srow * 32 + scol]        = pb0;
            *(uint4*)&Bs[(srow + 64) * 32 + scol] = pb1;
        }
        __syncthreads();

        const int kn = k0 + 32;
        if (kn < E_) {
            a00 = *(const float4*)(Ap + kn);
            a01 = *(const float4*)(Ap + kn + 4);
            a10 = *(const float4*)(Ap + kn + 64 * E_);
            a11 = *(const float4*)(Ap + kn + 64 * E_ + 4);
            b00 = *(const float4*)(Bp + kn);
            b01 = *(const float4*)(Bp + kn + 4);
            b10 = *(const float4*)(Bp + kn + 64 * E_);
            b11 = *(const float4*)(Bp + kn + 64 * E_ + 4);
        }

        bf16x8 af[4], bfr[4];
        #pragma unroll
        for (int i = 0; i < 4; i++)
            af[i]  = *(const bf16x8*)&As[(wm + i * 16 + l16) * 32 + quad * 8];
        #pragma unroll
        for (int i = 0; i < 4; i++)
            bfr[i] = *(const bf16x8*)&Bs[(wn + i * 16 + l16) * 32 + quad * 8];

        #pragma unroll
        for (int i = 0; i < 4; i++)
            #pragma unroll
            for (int j = 0; j < 4; j++)
                acc[i][j] = __builtin_amdgcn_mfma_f32_16x16x32_bf16(
                    af[i], bfr[j], acc[i][j], 0, 0, 0);
    }

    #pragma unroll
    for (int j = 0; j < 4; j++) {
        const int n = n0 + wn + j * 16 + l16;           // 0..6143
        const float bv = bias[n];
        const int which = n >> 11;                      // 0=q 1=k 2=v
        const int h = (n >> 7) & 15;
        const int d = n & 127;
        unsigned short* dst = (which == 0) ? qb : ((which == 1) ? kb : vb);
        #pragma unroll
        for (int i = 0; i < 4; i++) {
            #pragma unroll
            for (int r = 0; r < 4; r++) {
                const int m  = m0 + wm + i * 16 + quad * 4 + r;  // 0..4095
                const int bb = m >> 11;
                const int s  = m & (S_ - 1);
                dst[((size_t)(bb * NH_ + h) * S_ + s) * HD_ + d] = f2b(acc[i][j][r] + bv);
            }
        }
    }
}

// ---------------------------------------------------------------------------
// Kernel 2: in-place RoPE on q and k (bf16, fp32 math). Layout [B][NH][S][HD].
// ---------------------------------------------------------------------------
__global__ void rope_inplace(unsigned short* __restrict__ qb,
                             unsigned short* __restrict__ kb)
{
    const int idx = blockIdx.x * 256 + threadIdx.x;     // B*NH*S*16 exactly
    const int i   = idx & 15;
    const int s   = (idx >> 4) & (S_ - 1);
    const int bh  = idx >> 15;
    const float inv = exp2f(-0.83048202372184059f * (float)i); // log2(1e4)/16
    const float ang = (float)s * inv;
    const float c  = cosf(ang);
    const float sn = sinf(ang);
    const int base = (bh * S_ + s) * HD_;
    {
        float u1 = b2f(qb[base + i]), u2 = b2f(qb[base + i + 16]);
        qb[base + i]      = f2b(u1 * c - u2 * sn);
        qb[base + i + 16] = f2b(u1 * sn + u2 * c);
    }
    {
        float u1 = b2f(kb[base + i]), u2 = b2f(kb[base + i + 16]);
        kb[base + i]      = f2b(u1 * c - u2 * sn);
        kb[base + i + 16] = f2b(u1 * sn + u2 * c);
    }
}

// ---------------------------------------------------------------------------
// Kernel 3: MFMA causal flash attention. Round-5 restructure:
//  * wave owns 32 q-rows (2 m-blocks of 16) -> every K/V LDS fragment read
//    feeds 2 MFMAs (was 1); block = 128 q-rows; block-iters halved.
//  * register prefetch of next K/V tile kept; O epilogue via LDS kept
//    (run twice, one m-block at a time, barrier between passes).
// Layouts (HW-verified 16x16x32_bf16): A[m=lane&15][k=quad*8+j];
// C/D row=quad*4+reg, col=lane&15.
// ---------------------------------------------------------------------------
#define KSTR 136
#define VSTR 72
#define PSTR 72
#define OSTR 132

__global__ __launch_bounds__(256, 2) void attn_mfma(
    const unsigned short* __restrict__ qb,
    const unsigned short* __restrict__ kb,
    const unsigned short* __restrict__ vb,
    float* __restrict__ out)
{
    union SM {
        struct {
            unsigned short Ks[64 * KSTR];      // 17408 B
            unsigned short Vt[128 * VSTR];     // 18432 B
            unsigned short Ps[4 * 32 * PSTR];  // 18432 B
        } a;
        float Ow[4 * 16 * OSTR];               // 33792 B (epilogue reuse)
    };
    __shared__ __align__(16) SM sm;
    unsigned short* Ks = sm.a.Ks;
    unsigned short* Vt = sm.a.Vt;
    unsigned short* Ps = sm.a.Ps;

    const int qt   = (int)gridDim.x - 1 - (int)blockIdx.x;    // heavy first
    const int bh   = blockIdx.y;
    const int b    = bh >> 4;
    const int h    = bh & 15;
    const int t    = threadIdx.x;
    const int lane = t & 63;
    const int w    = t >> 6;
    const int quad = lane >> 4;
    const int l16  = lane & 15;

    const int qb0    = qt * 128;            // block q-row base
    const int wrow0  = qb0 + w * 32;        // wave q-row base (32 rows)
    const int ntiles = 2 * qt + 2;          // K tiles of 64

    unsigned short* Pw = Ps + w * 32 * PSTR;

    // staging maps
    const int krow = t >> 2, kcb = (t & 3) * 32;   // K: row, col-block
    const int vq   = t & 31, vd0 = (t >> 5) * 16;  // V: s-pair, d-block

    // Q A-fragments from global: m-block mb, k = c*32 + quad*8 + j
    bf16x8 qf[2][4];
    #pragma unroll
    for (int mb = 0; mb < 2; mb++) {
        const unsigned short* qp =
            qb + ((size_t)(bh * S_ + wrow0 + mb * 16 + l16)) * HD_ + quad * 8;
        #pragma unroll
        for (int c = 0; c < 4; c++)
            qf[mb][c] = *(const bf16x8*)(qp + c * 32);
    }

    f32x4 of[2][8];
    #pragma unroll
    for (int mb = 0; mb < 2; mb++)
        #pragma unroll
        for (int db = 0; db < 8; db++)
            #pragma unroll
            for (int r = 0; r < 4; r++) of[mb][db][r] = 0.0f;
    float mr[2][4], lr[2][4];
    #pragma unroll
    for (int mb = 0; mb < 2; mb++)
        #pragma unroll
        for (int r = 0; r < 4; r++) { mr[mb][r] = -1e30f; lr[mb][r] = 0.0f; }

    const float scale = 0.088388347648318447f;   // 1/sqrt(128)

    // prefetch registers
    uint4 kr[4];
    uint4 v0a, v0b, v1a, v1b;

    auto issue_tile = [&](int kt2) {
        const int s2 = kt2 * 64;
        const unsigned short* kg = kb + ((size_t)(bh * S_ + s2 + krow)) * HD_ + kcb;
        #pragma unroll
        for (int u = 0; u < 4; u++) kr[u] = *(const uint4*)(kg + u * 8);
        const unsigned short* vg = vb + ((size_t)(bh * S_ + s2 + 2 * vq)) * HD_ + vd0;
        v0a = *(const uint4*)(vg);
        v0b = *(const uint4*)(vg + 8);
        v1a = *(const uint4*)(vg + HD_);
        v1b = *(const uint4*)(vg + HD_ + 8);
    };

    issue_tile(0);

    for (int kt = 0; kt < ntiles; kt++) {
        const int s0 = kt * 64;
        __syncthreads();                  // prior iter's LDS readers done
        // ---- K tile -> LDS (row-major, b128)
        #pragma unroll
        for (int u = 0; u < 4; u++)
            *(uint4*)&Ks[krow * KSTR + kcb + u * 8] = kr[u];
        // ---- V tile -> LDS transposed: Vt[d][s], s-pairs packed as b32
        {
            unsigned int r0[8] = { v0a.x, v0a.y, v0a.z, v0a.w,
                                   v0b.x, v0b.y, v0b.z, v0b.w };
            unsigned int r1[8] = { v1a.x, v1a.y, v1a.z, v1a.w,
                                   v1b.x, v1b.y, v1b.z, v1b.w };
            #pragma unroll
            for (int j = 0; j < 16; j++) {
                const int u = j >> 1;
                unsigned int pk;
                if ((j & 1) == 0)
                    pk = (r0[u] & 0xffffu) | (r1[u] << 16);
                else
                    pk = (r0[u] >> 16) | (r1[u] & 0xffff0000u);
                *(unsigned int*)&Vt[(vd0 + j) * VSTR + 2 * vq] = pk;
            }
        }
        __syncthreads();

        if (kt + 1 < ntiles) issue_tile(kt + 1);

        // ---- S = Q K^T : m-blocks x 4 nb; kf reused across m-blocks
        f32x4 sf[2][4];
        #pragma unroll
        for (int mb = 0; mb < 2; mb++)
            #pragma unroll
            for (int nb = 0; nb < 4; nb++)
                #pragma unroll
                for (int r = 0; r < 4; r++) sf[mb][nb][r] = 0.0f;
        #pragma unroll
        for (int c = 0; c < 4; c++) {
            #pragma unroll
            for (int nb = 0; nb < 4; nb++) {
                bf16x8 kf = *(const bf16x8*)&Ks[(nb * 16 + l16) * KSTR + c * 32 + quad * 8];
                #pragma unroll
                for (int mb = 0; mb < 2; mb++)
                    sf[mb][nb] = __builtin_amdgcn_mfma_f32_16x16x32_bf16(
                        qf[mb][c], kf, sf[mb][nb], 0, 0, 0);
            }
        }

        // ---- scale + causal mask (only when this tile can cross the diag)
        const bool need_mask = (s0 + 63 > wrow0);
        #pragma unroll
        for (int mb = 0; mb < 2; mb++) {
            const int qr0 = wrow0 + mb * 16 + quad * 4;
            #pragma unroll
            for (int nb = 0; nb < 4; nb++) {
                const int kcol = s0 + nb * 16 + l16;
                #pragma unroll
                for (int r = 0; r < 4; r++) {
                    float s = sf[mb][nb][r] * scale;
                    if (need_mask && kcol > qr0 + r) s += -10000.0f;
                    sf[mb][nb][r] = s;
                }
            }
        }

        // ---- online softmax per m-block (row reduce over 16-lane group)
        #pragma unroll
        for (int mb = 0; mb < 2; mb++) {
            float alpha[4];
            #pragma unroll
            for (int r = 0; r < 4; r++) {
                float mt = fmaxf(fmaxf(sf[mb][0][r], sf[mb][1][r]),
                                 fmaxf(sf[mb][2][r], sf[mb][3][r]));
                mt = fmaxf(mt, __shfl_xor(mt, 1));
                mt = fmaxf(mt, __shfl_xor(mt, 2));
                mt = fmaxf(mt, __shfl_xor(mt, 4));
                mt = fmaxf(mt, __shfl_xor(mt, 8));
                const float mnew = fmaxf(mr[mb][r], mt);
                alpha[r] = __expf(mr[mb][r] - mnew);
                mr[mb][r] = mnew;
            }
            #pragma unroll
            for (int r = 0; r < 4; r++) {
                float rs = 0.0f;
                #pragma unroll
                for (int nb = 0; nb < 4; nb++) {
                    float p = __expf(sf[mb][nb][r] - mr[mb][r]);
                    sf[mb][nb][r] = p;
                    rs += p;
                }
                rs += __shfl_xor(rs, 1);
                rs += __shfl_xor(rs, 2);
                rs += __shfl_xor(rs, 4);
                rs += __shfl_xor(rs, 8);
                lr[mb][r] = lr[mb][r] * alpha[r] + rs;
            }
            #pragma unroll
            for (int db = 0; db < 8; db++)
                #pragma unroll
                for (int r = 0; r < 4; r++) of[mb][db][r] *= alpha[r];

            // P: C-layout -> wave-private LDS [m][s]
            #pragma unroll
            for (int nb = 0; nb < 4; nb++)
                #pragma unroll
                for (int r = 0; r < 4; r++)
                    Pw[(mb * 16 + quad * 4 + r) * PSTR + nb * 16 + l16] =
                        f2b(sf[mb][nb][r]);
        }

        // ---- O += P V : vf reused across m-blocks
        #pragma unroll
        for (int kc = 0; kc < 2; kc++) {
            bf16x8 pf[2];
            #pragma unroll
            for (int mb = 0; mb < 2; mb++)
                pf[mb] = *(const bf16x8*)&Pw[(mb * 16 + l16) * PSTR + kc * 32 + quad * 8];
            #pragma unroll
            for (int db = 0; db < 8; db++) {
                bf16x8 vf = *(const bf16x8*)&Vt[(db * 16 + l16) * VSTR + kc * 32 + quad * 8];
                #pragma unroll
                for (int mb = 0; mb < 2; mb++)
                    of[mb][db] = __builtin_amdgcn_mfma_f32_16x16x32_bf16(
                        pf[mb], vf, of[mb][db], 0, 0, 0);
            }
        }
    }

    // ---- epilogue: normalize, LDS transpose, coalesced float4 stores.
    // One m-block per pass; barrier between passes (union WAR safety).
    float* Ow = sm.Ow + w * 16 * OSTR;     // wave-private 16x132 fp32
    #pragma unroll
    for (int mb = 0; mb < 2; mb++) {
        __syncthreads();                   // readers of Ks/Vt/Ps (or pass 0) done
        float inv[4];
        #pragma unroll
        for (int r = 0; r < 4; r++) inv[r] = 1.0f / lr[mb][r];
        #pragma unroll
        for (int db = 0; db < 8; db++)
            #pragma unroll
            for (int r = 0; r < 4; r++)
                Ow[(quad * 4 + r) * OSTR + db * 16 + l16] = of[mb][db][r] * inv[r];
        #pragma unroll
        for (int rg = 0; rg < 4; rg++) {
            const int rowl = rg * 4 + quad;
            float* op = out + ((size_t)(b * S_ + wrow0 + mb * 16 + rowl)) * E_ + h * HD_;
            #pragma unroll
            for (int u = 0; u < 2; u++) {
                float4 v4 = *(const float4*)&Ow[rowl * OSTR + u * 64 + l16 * 4];
                *(float4*)(op + u * 64 + l16 * 4) = v4;
            }
        }
    }
}

// ---------------------------------------------------------------------------
extern "C" void kernel_launch(void* const* d_in, const int* in_sizes, int n_in,
                              void* d_out, int out_size, void* d_ws, size_t ws_size,
                              hipStream_t stream)
{
    const float* x    = (const float*)d_in[0];   // fp32 (B,S,E)
    const float* W    = (const float*)d_in[1];   // fp32 (6144,2048)
    const float* bias = (const float*)d_in[2];   // fp32 (6144,)
    float* out = (float*)d_out;                  // fp32 (B,S,E)

    const size_t per = (size_t)B_ * NH_ * S_ * HD_;               // 8388608
    unsigned short* qb = (unsigned short*)d_ws;                   // [B][NH][S][HD]
    unsigned short* kb = qb + per;                                // [B][NH][S][HD]
    unsigned short* vb = kb + per;                                // [B][NH][S][HD]

    dim3 gemm_grid(NQKV_ / 128, M_ / 128);                        // 48 x 32
    qkv_gemm<<<gemm_grid, 256, 0, stream>>>(x, W, bias, qb, kb, vb);

    rope_inplace<<<(B_ * NH_ * S_ * 16) / 256, 256, 0, stream>>>(qb, kb);

    dim3 attn_grid(S_ / 128, B_ * NH_);                           // 16 x 32
    attn_mfma<<<attn_grid, 256, 0, stream>>>(qb, kb, vb, out);
}